// Round 7
// baseline (6999.262 us; speedup 1.0000x reference)
//
#include <hip/hip_runtime.h>

// ---------------------------------------------------------------------------
// Persistent 2-layer LSTM, MI355X. Round 7: LAYER-PIPELINED.
// 8 groups (blockIdx%8), 32 WGs/group: 16 L0-WGs own layer 0, 16 L1-WGs own
// layer 1 (32 units x 4 gates each, 2 MFMA n-tiles). Each layer's recurrence
// crosses the group ONCE per step and the two layers run concurrently
// (L1 lags L0 by one step) -> 1 crossing on the critical path instead of 2.
// Out-projection runs in L1's wait window (off critical path).
// Coherence: relaxed SYSTEM-scope (sc0|sc1 bypass) loads/stores at LLC,
// per-WG monotone int flags, zero cache-maintenance ops (proven r3-r6).
// Back-pressure: L0 waits flag1 >= t-1 so h0(t-2) is consumed before
// overwrite (2-deep parity planes).
// ---------------------------------------------------------------------------

#define T_STEPS 1024
#define WS_BAR_OFF 0                      // 8 groups * 64 ints
#define WS_H0_OFF  2048                   // [8 g][2 parity][16 wg][8 b][32 u] f16
#define WS_H1_OFF  (2048 + 8*2*8*512*2)
#define WS_NEED    (WS_H1_OFF + 8*2*8*512*2)   // 264192 bytes

typedef _Float16 f16;
typedef _Float16 f16x8 __attribute__((ext_vector_type(8)));
typedef float    f32x4 __attribute__((ext_vector_type(4)));
typedef unsigned long long u64;

#define HP_STRIDE 520   // padded LDS plane row stride (f16)

__device__ __forceinline__ float sigm_(float x) {
    x = fminf(fmaxf(x, -30.f), 30.f);
    return 1.f / (1.f + __expf(-x));
}
__device__ __forceinline__ float tanh_(float x) {
    x = fminf(fmaxf(x, -15.f), 15.f);
    float e = __expf(-2.f * x);
    return (1.f - e) / (1.f + e);
}

// A-fragment for 16x16x32 f16 MFMA from a padded LDS plane.
// A[m=lane&15][k=(lane>>4)*8+j]; m = batch (0..7 valid, 8..15 -> zeros).
__device__ __forceinline__ f16x8 afrag_lds(const f16* __restrict__ hp, int kbase,
                                           int b, int q) {
    if (b < 8) {
        return *(const f16x8*)(hp + b * HP_STRIDE + kbase + q * 8);
    }
    f16x8 z = {(_Float16)0, (_Float16)0, (_Float16)0, (_Float16)0,
               (_Float16)0, (_Float16)0, (_Float16)0, (_Float16)0};
    return z;
}

__device__ __forceinline__ f16x8 pack8(const float* p) {
    float4 a = *(const float4*)p, b = *(const float4*)(p + 4);
    f16x8 f;
    f[0] = (f16)a.x; f[1] = (f16)a.y; f[2] = (f16)a.z; f[3] = (f16)a.w;
    f[4] = (f16)b.x; f[5] = (f16)b.y; f[6] = (f16)b.z; f[7] = (f16)b.w;
    return f;
}

// Wait until all 16 flag0 >= t0 AND all 16 flag1 >= t1. One load per lane
// (lanes 0-15: flag0, 16-31: flag1, 32-63 duplicate), __all vote, short sleep.
__device__ __forceinline__ void wait_flags(const int* f0, int t0,
                                           const int* f1, int t1, int lane) {
    const int* p = (lane & 16) ? (f1 + (lane & 15)) : (f0 + (lane & 15));
    const int tgt = (lane & 16) ? t1 : t0;
    int spins = 0;
    for (;;) {
        int v = __hip_atomic_load(p, __ATOMIC_RELAXED, __HIP_MEMORY_SCOPE_SYSTEM);
        if (__all(v >= tgt)) break;
        __builtin_amdgcn_s_sleep(2);
        if (++spins > (1 << 20)) break;   // anti-hang safety valve
    }
}

// Stage one 8 KB h-plane ([16 wg][8 b][32 u] f16, WG-major global) into the
// padded LDS [batch][unit 0..511] plane. u64 i: wg=i>>6, b=(i>>3)&7, j=i&7.
__device__ __forceinline__ void stage_plane(const f16* __restrict__ gp,
                                            f16* __restrict__ dst, int tid) {
    const u64* g8 = (const u64*)gp;
    u64 v[4];
#pragma unroll
    for (int jj = 0; jj < 4; ++jj)
        v[jj] = __hip_atomic_load(g8 + jj * 256 + tid, __ATOMIC_RELAXED,
                                  __HIP_MEMORY_SCOPE_SYSTEM);
#pragma unroll
    for (int jj = 0; jj < 4; ++jj) {
        int i = jj * 256 + tid;
        int wg = i >> 6, b = (i >> 3) & 7, j = i & 7;
        *(u64*)(dst + b * HP_STRIDE + wg * 32 + j * 4) = v[jj];
    }
}

// x A-fragment for step t.
__device__ __forceinline__ f16x8 load_xfrag(const float* __restrict__ x,
                                            int gb8, int t, int ln, int q) {
    f16x8 f = {(_Float16)0, (_Float16)0, (_Float16)0, (_Float16)0,
               (_Float16)0, (_Float16)0, (_Float16)0, (_Float16)0};
    if (ln < 8 && t < T_STEPS) {
        const float* xp = x + ((size_t)(gb8 + ln) * 1024 + t) * 21;
#pragma unroll
        for (int j = 0; j < 8; ++j) {
            int kl = q * 8 + j;
            if (kl < 21) f[j] = (f16)xp[kl];
        }
    }
    return f;
}

// Zeros must be visible at the LLC -> sc0sc1 stores.
__global__ void zero_ws_kernel(unsigned* __restrict__ p, int ndw) {
    int i = blockIdx.x * blockDim.x + threadIdx.x;
    int stride = gridDim.x * blockDim.x;
    for (; i < ndw; i += stride)
        __hip_atomic_store(p + i, 0u, __ATOMIC_RELAXED, __HIP_MEMORY_SCOPE_SYSTEM);
}

__global__ __launch_bounds__(256, 1)
void lstm_persist(const float* __restrict__ x,
                  const float* __restrict__ Wx0, const float* __restrict__ bx0,
                  const float* __restrict__ Wh0,
                  const float* __restrict__ Wx1, const float* __restrict__ bx1,
                  const float* __restrict__ Wh1,
                  const float* __restrict__ Wo,  const float* __restrict__ bo,
                  float* __restrict__ out, char* __restrict__ ws) {
    struct SM {
        float g[4][8][33];                       // gate tiles [gate][b][u0..31]+pad
        float c[8][32];                          // this WG's cell state
        float bias[4][32];                       // this WG's bias slice
        __align__(8)  f16 hout[8][32];           // activation -> packed store
        __align__(16) f16 planeA[8 * HP_STRIDE]; // h0 plane
        __align__(16) f16 planeB[8 * HP_STRIDE]; // h1 plane (L1 only)
        char  pad[60 * 1024];                    // force 1 WG/CU
    };
    __shared__ SM sm;
    const int tid = threadIdx.x;
    if (tid == 0x00FFFFFFu) sm.pad[0] = 1;       // keep pad alive

    const int bid  = blockIdx.x;
    const int g    = bid & 7;        // group (XCD-affine under round-robin)
    const int rk   = bid >> 3;       // 0..31 within group
    const int role = rk >> 4;        // 0: layer-0 WG, 1: layer-1 WG
    const int r    = rk & 15;        // rank within role
    const int w    = tid >> 6;       // wave id = gate type (i,f,g,o)
    const int lane = tid & 63;
    const int ln   = lane & 15;
    const int q    = lane >> 4;
    const int gb8  = g * 8;

    int* barb  = (int*)(ws + WS_BAR_OFF) + g * 64;
    int* flag0 = barb;               // 16 per-L0-WG monotone step flags
    int* flag1 = barb + 16;          // 16 per-L1-WG flags
    f16* H0g = (f16*)(ws + WS_H0_OFF) + g * 8192;   // 2 parity planes
    f16* H1g = (f16*)(ws + WS_H1_OFF) + g * 8192;

    // ---- LDS init -------------------------------------------------------
    ((float*)sm.c)[tid] = 0.f;                   // 8*32 = 256 floats
    if (tid < 128) {
        int gate = tid >> 5, u = tid & 31;
        const float* bx = role ? bx1 : bx0;
        sm.bias[gate][u] = bx[(gate << 9) + (r << 5) + u];
    }

    // ---- persistent weight fragments in registers -----------------------
    // W[ ]: role 0 -> W[tau*17+kk] (K=544: Wh0|Wx0pad), tau in {0,1} n-tiles.
    //       role 1 -> W[tau*32+kk] (K=1024: Wx1|Wh1).
    f16x8 W[64];
    if (role == 0) {
#pragma unroll
        for (int tau = 0; tau < 2; ++tau) {
            const int rw = (w << 9) + (r << 5) + tau * 16 + ln;
            const float* wh0r = Wh0 + (size_t)rw * 512;
#pragma unroll
            for (int kk = 0; kk < 16; ++kk)
                W[tau * 17 + kk] = pack8(wh0r + kk * 32 + q * 8);
            const float* wx0r = Wx0 + (size_t)rw * 21;
            f16x8 f = {(_Float16)0, (_Float16)0, (_Float16)0, (_Float16)0,
                       (_Float16)0, (_Float16)0, (_Float16)0, (_Float16)0};
#pragma unroll
            for (int j = 0; j < 8; ++j) {
                int kl = q * 8 + j;
                if (kl < 21) f[j] = (f16)wx0r[kl];
            }
            W[tau * 17 + 16] = f;
        }
    } else {
#pragma unroll
        for (int tau = 0; tau < 2; ++tau) {
            const int rw = (w << 9) + (r << 5) + tau * 16 + ln;
            const float* wx1r = Wx1 + (size_t)rw * 512;
            const float* wh1r = Wh1 + (size_t)rw * 512;
#pragma unroll
            for (int kk = 0; kk < 16; ++kk)
                W[tau * 32 + kk] = pack8(wx1r + kk * 32 + q * 8);
#pragma unroll
            for (int kk = 16; kk < 32; ++kk)
                W[tau * 32 + kk] = pack8(wh1r + (kk - 16) * 32 + q * 8);
        }
    }
    __syncthreads();

    if (role == 0) {
        // =================== layer-0 pipeline stage =======================
        for (int t = 0; t < T_STEPS; ++t) {
            const int wr = t & 1, rd = wr ^ 1;
            f16x8 xf = load_xfrag(x, gb8, t, ln, q);   // prefetch before wait
            // need h0(t-1) (all flag0>=t) and h0(t-2) consumed by L1
            // (flag1>=t-1). Planes zeroed => t=0 reads h0(-1)=0 uniformly.
            wait_flags(flag0, t, flag1, t - 1, lane);
            stage_plane(H0g + rd * 4096, sm.planeA, tid);
            __syncthreads();

            f32x4 a0 = {0, 0, 0, 0}, a1 = {0, 0, 0, 0};
#pragma unroll
            for (int kk = 0; kk < 16; ++kk) {
                f16x8 A = afrag_lds(sm.planeA, kk * 32, ln, q);
                a0 = __builtin_amdgcn_mfma_f32_16x16x32_f16(A, W[kk], a0, 0, 0, 0);
                a1 = __builtin_amdgcn_mfma_f32_16x16x32_f16(A, W[17 + kk], a1, 0, 0, 0);
            }
            a0 = __builtin_amdgcn_mfma_f32_16x16x32_f16(xf, W[16], a0, 0, 0, 0);
            a1 = __builtin_amdgcn_mfma_f32_16x16x32_f16(xf, W[33], a1, 0, 0, 0);
            if (q < 2) {
#pragma unroll
                for (int r4 = 0; r4 < 4; ++r4) {
                    sm.g[w][q * 4 + r4][ln] = a0[r4];
                    sm.g[w][q * 4 + r4][16 + ln] = a1[r4];
                }
            }
            __syncthreads();
            {   // activation: 8 batches x 32 units = 256 threads
                int b = tid >> 5, u = tid & 31;
                float gi = sm.g[0][b][u] + sm.bias[0][u];
                float gf = sm.g[1][b][u] + sm.bias[1][u];
                float gg = sm.g[2][b][u] + sm.bias[2][u];
                float go = sm.g[3][b][u] + sm.bias[3][u];
                float iv = sigm_(gi), fv = sigm_(gf), gv = tanh_(gg), ov = sigm_(go);
                float c = sm.c[b][u];
                float cn = fv * c + iv * gv;
                sm.c[b][u] = cn;
                sm.hout[b][u] = (f16)(ov * tanh_(cn));
            }
            __syncthreads();
            if (tid < 64) {   // 512 B contiguous WG slice, wave-0 only
                int b = tid >> 3, j = tid & 7;
                u64 v = *(const u64*)&sm.hout[b][j * 4];
                __hip_atomic_store((u64*)(H0g + wr * 4096 + (r << 8) + (b << 5) + (j << 2)),
                                   v, __ATOMIC_RELAXED, __HIP_MEMORY_SCOPE_SYSTEM);
                asm volatile("s_waitcnt vmcnt(0)" ::: "memory");
                if (tid == 0)
                    __hip_atomic_store(flag0 + r, t + 1, __ATOMIC_RELAXED,
                                       __HIP_MEMORY_SCOPE_SYSTEM);
            }
        }
    } else {
        // =================== layer-1 pipeline stage =======================
        for (int t = 0; t < T_STEPS; ++t) {
            const int wr = t & 1, rd = wr ^ 1;
            // need h1(t-1); flag0>=t already implied by completing step t-1
            wait_flags(flag0, t, flag1, t, lane);
            stage_plane(H1g + rd * 4096, sm.planeB, tid);
            __syncthreads();

            // out-proj(t-1) from planeB, in the wait window: 10 (b,o) pairs
            if (t > 0) {
                int p = tid >> 4, kp = tid & 15;
                int valid = (p < 10);
                int idx = r * 10 + p;
                int b = valid ? idx / 20 : 0, o = valid ? idx % 20 : 0;
                float a = 0.f;
                if (valid) {
                    const f16* hp = sm.planeB + b * HP_STRIDE + kp * 32;
                    const float* wo = Wo + (size_t)o * 512 + kp * 32;
#pragma unroll
                    for (int k = 0; k < 32; k += 8) {
                        f16x8 hv = *(const f16x8*)(hp + k);
                        float4 wa = *(const float4*)(wo + k);
                        float4 wb = *(const float4*)(wo + k + 4);
                        a += (float)hv[0] * wa.x + (float)hv[1] * wa.y +
                             (float)hv[2] * wa.z + (float)hv[3] * wa.w +
                             (float)hv[4] * wb.x + (float)hv[5] * wb.y +
                             (float)hv[6] * wb.z + (float)hv[7] * wb.w;
                    }
                }
                a += __shfl_down(a, 8, 16);
                a += __shfl_down(a, 4, 16);
                a += __shfl_down(a, 2, 16);
                a += __shfl_down(a, 1, 16);
                if (valid && kp == 0)
                    out[((size_t)(gb8 + b) * 1024 + (t - 1)) * 20 + o] =
                        sigm_(a + bo[o]);
            }

            // need h0(t): fresh crossing from the L0 stage
            wait_flags(flag0, t + 1, flag1, t, lane);
            stage_plane(H0g + wr * 4096, sm.planeA, tid);
            __syncthreads();

            f32x4 a0 = {0, 0, 0, 0}, a1 = {0, 0, 0, 0};
#pragma unroll
            for (int kk = 0; kk < 16; ++kk) {
                f16x8 A = afrag_lds(sm.planeA, kk * 32, ln, q);
                a0 = __builtin_amdgcn_mfma_f32_16x16x32_f16(A, W[kk], a0, 0, 0, 0);
                a1 = __builtin_amdgcn_mfma_f32_16x16x32_f16(A, W[32 + kk], a1, 0, 0, 0);
            }
#pragma unroll
            for (int kk = 16; kk < 32; ++kk) {
                f16x8 A = afrag_lds(sm.planeB, (kk - 16) * 32, ln, q);
                a0 = __builtin_amdgcn_mfma_f32_16x16x32_f16(A, W[kk], a0, 0, 0, 0);
                a1 = __builtin_amdgcn_mfma_f32_16x16x32_f16(A, W[32 + kk], a1, 0, 0, 0);
            }
            if (q < 2) {
#pragma unroll
                for (int r4 = 0; r4 < 4; ++r4) {
                    sm.g[w][q * 4 + r4][ln] = a0[r4];
                    sm.g[w][q * 4 + r4][16 + ln] = a1[r4];
                }
            }
            __syncthreads();
            {
                int b = tid >> 5, u = tid & 31;
                float gi = sm.g[0][b][u] + sm.bias[0][u];
                float gf = sm.g[1][b][u] + sm.bias[1][u];
                float gg = sm.g[2][b][u] + sm.bias[2][u];
                float go = sm.g[3][b][u] + sm.bias[3][u];
                float iv = sigm_(gi), fv = sigm_(gf), gv = tanh_(gg), ov = sigm_(go);
                float c = sm.c[b][u];
                float cn = fv * c + iv * gv;
                sm.c[b][u] = cn;
                sm.hout[b][u] = (f16)(ov * tanh_(cn));
            }
            __syncthreads();
            if (tid < 64) {
                int b = tid >> 3, j = tid & 7;
                u64 v = *(const u64*)&sm.hout[b][j * 4];
                __hip_atomic_store((u64*)(H1g + wr * 4096 + (r << 8) + (b << 5) + (j << 2)),
                                   v, __ATOMIC_RELAXED, __HIP_MEMORY_SCOPE_SYSTEM);
                asm volatile("s_waitcnt vmcnt(0)" ::: "memory");
                if (tid == 0)
                    __hip_atomic_store(flag1 + r, t + 1, __ATOMIC_RELAXED,
                                       __HIP_MEMORY_SCOPE_SYSTEM);
            }
        }

        // ===== epilogue: out(T-1) from h1(T-1) =============================
        wait_flags(flag0, T_STEPS, flag1, T_STEPS, lane);
        stage_plane(H1g + ((T_STEPS - 1) & 1) * 4096, sm.planeB, tid);
        __syncthreads();
        {
            int p = tid >> 4, kp = tid & 15;
            int valid = (p < 10);
            int idx = r * 10 + p;
            int b = valid ? idx / 20 : 0, o = valid ? idx % 20 : 0;
            float a = 0.f;
            if (valid) {
                const f16* hp = sm.planeB + b * HP_STRIDE + kp * 32;
                const float* wo = Wo + (size_t)o * 512 + kp * 32;
#pragma unroll
                for (int k = 0; k < 32; k += 8) {
                    f16x8 hv = *(const f16x8*)(hp + k);
                    float4 wa = *(const float4*)(wo + k);
                    float4 wb = *(const float4*)(wo + k + 4);
                    a += (float)hv[0] * wa.x + (float)hv[1] * wa.y +
                         (float)hv[2] * wa.z + (float)hv[3] * wa.w +
                         (float)hv[4] * wb.x + (float)hv[5] * wb.y +
                         (float)hv[6] * wb.z + (float)hv[7] * wb.w;
                }
            }
            a += __shfl_down(a, 8, 16);
            a += __shfl_down(a, 4, 16);
            a += __shfl_down(a, 2, 16);
            a += __shfl_down(a, 1, 16);
            if (valid && kp == 0)
                out[((size_t)(gb8 + b) * 1024 + (T_STEPS - 1)) * 20 + o] =
                    sigm_(a + bo[o]);
        }
    }
}

extern "C" void kernel_launch(void* const* d_in, const int* in_sizes, int n_in,
                              void* d_out, int out_size, void* d_ws, size_t ws_size,
                              hipStream_t stream) {
    const float* x   = (const float*)d_in[0];
    const float* Wx0 = (const float*)d_in[1];
    const float* bx0 = (const float*)d_in[2];
    const float* Wh0 = (const float*)d_in[3];
    const float* Wx1 = (const float*)d_in[4];
    const float* bx1 = (const float*)d_in[5];
    const float* Wh1 = (const float*)d_in[6];
    const float* Wo  = (const float*)d_in[7];
    const float* bo  = (const float*)d_in[8];
    float* out = (float*)d_out;
    char*  ws  = (char*)d_ws;

    if (ws_size < (size_t)WS_NEED) return;   // fail visibly (out stays poisoned)

    zero_ws_kernel<<<64, 256, 0, stream>>>((unsigned*)ws, WS_NEED / 4);
    lstm_persist<<<256, 256, 0, stream>>>(x, Wx0, bx0, Wh0, Wx1, bx1, Wh1,
                                          Wo, bo, out, ws);
}

// Round 8
// 5757.624 us; speedup vs baseline: 1.2157x; 1.2157x over previous
//
#include <hip/hip_runtime.h>

// ---------------------------------------------------------------------------
// Persistent 2-layer LSTM, MI355X. Round 8: layer-pipelined + DEPTH-4 DECOUPLE.
// 8 groups (blockIdx%8), 32 WGs/group: 16 L0-WGs own layer 0, 16 L1-WGs own
// layer 1. Round-7 bug: depth-2 h0 planes + backpressure made L0/L1 strictly
// alternate (serial chain of both bodies + 2 crossings/step). Round-8: h0
// planes are 4 deep (L0 runs up to 3 steps ahead; waits flag1 >= t-3), so
// each stage's period contains ONE self-recurrence crossing overlapped with
// its peers' identical work. Out-proj moved after h1 publish (reads LDS).
// Coherence: relaxed SYSTEM-scope (sc0|sc1 bypass) ops at LLC, per-WG
// monotone int flags, zero cache-maintenance ops (proven r3-r7).
// ---------------------------------------------------------------------------

#define T_STEPS 1024
#define WS_BAR_OFF 0                      // 8 groups * 64 ints
#define WS_H0_OFF  2048                   // [8 g][4 depth][16 wg][8 b][32 u] f16
#define WS_H1_OFF  (2048 + 8*4*8192)      // [8 g][2 depth][...]    (266240)
#define WS_NEED    (WS_H1_OFF + 8*2*8192) // 397312 bytes

typedef _Float16 f16;
typedef _Float16 f16x8 __attribute__((ext_vector_type(8)));
typedef float    f32x4 __attribute__((ext_vector_type(4)));
typedef unsigned long long u64;

#define HP_STRIDE 520   // padded LDS plane row stride (f16)

__device__ __forceinline__ float sigm_(float x) {
    x = fminf(fmaxf(x, -30.f), 30.f);
    return 1.f / (1.f + __expf(-x));
}
__device__ __forceinline__ float tanh_(float x) {
    x = fminf(fmaxf(x, -15.f), 15.f);
    float e = __expf(-2.f * x);
    return (1.f - e) / (1.f + e);
}

// A-fragment for 16x16x32 f16 MFMA from a padded LDS plane.
// A[m=lane&15][k=(lane>>4)*8+j]; m = batch (0..7 valid, 8..15 -> zeros).
__device__ __forceinline__ f16x8 afrag_lds(const f16* __restrict__ hp, int kbase,
                                           int b, int q) {
    if (b < 8) {
        return *(const f16x8*)(hp + b * HP_STRIDE + kbase + q * 8);
    }
    f16x8 z = {(_Float16)0, (_Float16)0, (_Float16)0, (_Float16)0,
               (_Float16)0, (_Float16)0, (_Float16)0, (_Float16)0};
    return z;
}

__device__ __forceinline__ f16x8 pack8(const float* p) {
    float4 a = *(const float4*)p, b = *(const float4*)(p + 4);
    f16x8 f;
    f[0] = (f16)a.x; f[1] = (f16)a.y; f[2] = (f16)a.z; f[3] = (f16)a.w;
    f[4] = (f16)b.x; f[5] = (f16)b.y; f[6] = (f16)b.z; f[7] = (f16)b.w;
    return f;
}

// Wait until all 16 flag0 >= t0 AND all 16 flag1 >= t1. One load per lane
// (lanes 0-15: flag0, 16-31: flag1, 32-63 duplicate), __all vote, short sleep.
__device__ __forceinline__ void wait_flags(const int* f0, int t0,
                                           const int* f1, int t1, int lane) {
    const int* p = (lane & 16) ? (f1 + (lane & 15)) : (f0 + (lane & 15));
    const int tgt = (lane & 16) ? t1 : t0;
    int spins = 0;
    for (;;) {
        int v = __hip_atomic_load(p, __ATOMIC_RELAXED, __HIP_MEMORY_SCOPE_SYSTEM);
        if (__all(v >= tgt)) break;
        __builtin_amdgcn_s_sleep(1);
        if (++spins > (1 << 20)) break;   // anti-hang safety valve
    }
}

// Stage one 8 KB h-plane ([16 wg][8 b][32 u] f16, WG-major global) into the
// padded LDS [batch][unit 0..511] plane. u64 i: wg=i>>6, b=(i>>3)&7, j=i&7.
__device__ __forceinline__ void stage_plane(const f16* __restrict__ gp,
                                            f16* __restrict__ dst, int tid) {
    const u64* g8 = (const u64*)gp;
    u64 v[4];
#pragma unroll
    for (int jj = 0; jj < 4; ++jj)
        v[jj] = __hip_atomic_load(g8 + jj * 256 + tid, __ATOMIC_RELAXED,
                                  __HIP_MEMORY_SCOPE_SYSTEM);
#pragma unroll
    for (int jj = 0; jj < 4; ++jj) {
        int i = jj * 256 + tid;
        int wg = i >> 6, b = (i >> 3) & 7, j = i & 7;
        *(u64*)(dst + b * HP_STRIDE + wg * 32 + j * 4) = v[jj];
    }
}

// x A-fragment for step t.
__device__ __forceinline__ f16x8 load_xfrag(const float* __restrict__ x,
                                            int gb8, int t, int ln, int q) {
    f16x8 f = {(_Float16)0, (_Float16)0, (_Float16)0, (_Float16)0,
               (_Float16)0, (_Float16)0, (_Float16)0, (_Float16)0};
    if (ln < 8 && t < T_STEPS) {
        const float* xp = x + ((size_t)(gb8 + ln) * 1024 + t) * 21;
#pragma unroll
        for (int j = 0; j < 8; ++j) {
            int kl = q * 8 + j;
            if (kl < 21) f[j] = (f16)xp[kl];
        }
    }
    return f;
}

// Zeros must be visible at the LLC -> sc0sc1 stores.
__global__ void zero_ws_kernel(unsigned* __restrict__ p, int ndw) {
    int i = blockIdx.x * blockDim.x + threadIdx.x;
    int stride = gridDim.x * blockDim.x;
    for (; i < ndw; i += stride)
        __hip_atomic_store(p + i, 0u, __ATOMIC_RELAXED, __HIP_MEMORY_SCOPE_SYSTEM);
}

__global__ __launch_bounds__(256, 1)
void lstm_persist(const float* __restrict__ x,
                  const float* __restrict__ Wx0, const float* __restrict__ bx0,
                  const float* __restrict__ Wh0,
                  const float* __restrict__ Wx1, const float* __restrict__ bx1,
                  const float* __restrict__ Wh1,
                  const float* __restrict__ Wo,  const float* __restrict__ bo,
                  float* __restrict__ out, char* __restrict__ ws) {
    struct SM {
        float g[4][8][33];                       // gate tiles [gate][b][u0..31]+pad
        float c[8][32];                          // this WG's cell state
        float bias[4][32];                       // this WG's bias slice
        __align__(8)  f16 hout[8][32];           // activation -> packed store
        __align__(16) f16 planeA[8 * HP_STRIDE]; // h0 plane
        __align__(16) f16 planeB[8 * HP_STRIDE]; // h1 plane (L1 only)
        char  pad[60 * 1024];                    // force 1 WG/CU
    };
    __shared__ SM sm;
    const int tid = threadIdx.x;
    if (tid == 0x00FFFFFFu) sm.pad[0] = 1;       // keep pad alive

    const int bid  = blockIdx.x;
    const int g    = bid & 7;        // group (XCD-affine under round-robin)
    const int rk   = bid >> 3;       // 0..31 within group
    const int role = rk >> 4;        // 0: layer-0 WG, 1: layer-1 WG
    const int r    = rk & 15;        // rank within role
    const int w    = tid >> 6;       // wave id = gate type (i,f,g,o)
    const int lane = tid & 63;
    const int ln   = lane & 15;
    const int q    = lane >> 4;
    const int gb8  = g * 8;

    int* barb  = (int*)(ws + WS_BAR_OFF) + g * 64;
    int* flag0 = barb;               // 16 per-L0-WG monotone step flags
    int* flag1 = barb + 16;          // 16 per-L1-WG flags
    f16* H0g = (f16*)(ws + WS_H0_OFF) + g * 16384;  // 4 depth planes
    f16* H1g = (f16*)(ws + WS_H1_OFF) + g * 8192;   // 2 depth planes

    // ---- LDS init -------------------------------------------------------
    ((float*)sm.c)[tid] = 0.f;                   // 8*32 = 256 floats
    if (tid < 128) {
        int gate = tid >> 5, u = tid & 31;
        const float* bx = role ? bx1 : bx0;
        sm.bias[gate][u] = bx[(gate << 9) + (r << 5) + u];
    }

    // ---- persistent weight fragments in registers -----------------------
    // W[ ]: role 0 -> W[tau*17+kk] (K=544: Wh0|Wx0pad), tau in {0,1} n-tiles.
    //       role 1 -> W[tau*32+kk] (K=1024: Wx1|Wh1).
    f16x8 W[64];
    if (role == 0) {
#pragma unroll
        for (int tau = 0; tau < 2; ++tau) {
            const int rw = (w << 9) + (r << 5) + tau * 16 + ln;
            const float* wh0r = Wh0 + (size_t)rw * 512;
#pragma unroll
            for (int kk = 0; kk < 16; ++kk)
                W[tau * 17 + kk] = pack8(wh0r + kk * 32 + q * 8);
            const float* wx0r = Wx0 + (size_t)rw * 21;
            f16x8 f = {(_Float16)0, (_Float16)0, (_Float16)0, (_Float16)0,
                       (_Float16)0, (_Float16)0, (_Float16)0, (_Float16)0};
#pragma unroll
            for (int j = 0; j < 8; ++j) {
                int kl = q * 8 + j;
                if (kl < 21) f[j] = (f16)wx0r[kl];
            }
            W[tau * 17 + 16] = f;
        }
    } else {
#pragma unroll
        for (int tau = 0; tau < 2; ++tau) {
            const int rw = (w << 9) + (r << 5) + tau * 16 + ln;
            const float* wx1r = Wx1 + (size_t)rw * 512;
            const float* wh1r = Wh1 + (size_t)rw * 512;
#pragma unroll
            for (int kk = 0; kk < 16; ++kk)
                W[tau * 32 + kk] = pack8(wx1r + kk * 32 + q * 8);
#pragma unroll
            for (int kk = 16; kk < 32; ++kk)
                W[tau * 32 + kk] = pack8(wh1r + (kk - 16) * 32 + q * 8);
        }
    }
    __syncthreads();

    if (role == 0) {
        // =================== layer-0 pipeline stage =======================
        // Writes h0(t) -> plane t&3. Backpressure: plane t&3 holds h0(t-4),
        // consumed by L1 step t-4 (flag1 >= t-3) and L0 step t-3 (flag0 >= t-2
        // implied by flag0 >= t). Up to 3 steps ahead of L1.
        for (int t = 0; t < T_STEPS; ++t) {
            const int wr = t & 3, rd = (t + 3) & 3;
            f16x8 xf = load_xfrag(x, gb8, t, ln, q);   // prefetch before wait
            wait_flags(flag0, t, flag1, t - 3, lane);
            stage_plane(H0g + rd * 4096, sm.planeA, tid);
            __syncthreads();

            f32x4 a0 = {0, 0, 0, 0}, a1 = {0, 0, 0, 0};
#pragma unroll
            for (int kk = 0; kk < 16; ++kk) {
                f16x8 A = afrag_lds(sm.planeA, kk * 32, ln, q);
                a0 = __builtin_amdgcn_mfma_f32_16x16x32_f16(A, W[kk], a0, 0, 0, 0);
                a1 = __builtin_amdgcn_mfma_f32_16x16x32_f16(A, W[17 + kk], a1, 0, 0, 0);
            }
            a0 = __builtin_amdgcn_mfma_f32_16x16x32_f16(xf, W[16], a0, 0, 0, 0);
            a1 = __builtin_amdgcn_mfma_f32_16x16x32_f16(xf, W[33], a1, 0, 0, 0);
            if (q < 2) {
#pragma unroll
                for (int r4 = 0; r4 < 4; ++r4) {
                    sm.g[w][q * 4 + r4][ln] = a0[r4];
                    sm.g[w][q * 4 + r4][16 + ln] = a1[r4];
                }
            }
            __syncthreads();
            {   // activation: 8 batches x 32 units = 256 threads
                int b = tid >> 5, u = tid & 31;
                float gi = sm.g[0][b][u] + sm.bias[0][u];
                float gf = sm.g[1][b][u] + sm.bias[1][u];
                float gg = sm.g[2][b][u] + sm.bias[2][u];
                float go = sm.g[3][b][u] + sm.bias[3][u];
                float iv = sigm_(gi), fv = sigm_(gf), gv = tanh_(gg), ov = sigm_(go);
                float c = sm.c[b][u];
                float cn = fv * c + iv * gv;
                sm.c[b][u] = cn;
                sm.hout[b][u] = (f16)(ov * tanh_(cn));
            }
            __syncthreads();
            if (tid < 64) {   // 512 B contiguous WG slice, wave-0 only
                int b = tid >> 3, j = tid & 7;
                u64 v = *(const u64*)&sm.hout[b][j * 4];
                __hip_atomic_store((u64*)(H0g + wr * 4096 + (r << 8) + (b << 5) + (j << 2)),
                                   v, __ATOMIC_RELAXED, __HIP_MEMORY_SCOPE_SYSTEM);
                asm volatile("s_waitcnt vmcnt(0)" ::: "memory");
                if (tid == 0)
                    __hip_atomic_store(flag0 + r, t + 1, __ATOMIC_RELAXED,
                                       __HIP_MEMORY_SCOPE_SYSTEM);
            }
        }
    } else {
        // =================== layer-1 pipeline stage =======================
        for (int t = 0; t < T_STEPS; ++t) {
            const int wr = t & 1, rd = wr ^ 1;

            // ---- h0(t) half first (L0 runs ahead -> wait usually instant) -
            wait_flags(flag0, t + 1, flag1, t - 1000000000, lane);
            stage_plane(H0g + (t & 3) * 4096, sm.planeA, tid);
            __syncthreads();
            f32x4 a0 = {0, 0, 0, 0}, a1 = {0, 0, 0, 0};
#pragma unroll
            for (int kk = 0; kk < 16; ++kk) {
                f16x8 A = afrag_lds(sm.planeA, kk * 32, ln, q);
                a0 = __builtin_amdgcn_mfma_f32_16x16x32_f16(A, W[kk], a0, 0, 0, 0);
                a1 = __builtin_amdgcn_mfma_f32_16x16x32_f16(A, W[32 + kk], a1, 0, 0, 0);
            }

            // ---- h1(t-1) half: the self-recurrence crossing ---------------
            wait_flags(flag0, t + 1, flag1, t, lane);
            stage_plane(H1g + rd * 4096, sm.planeB, tid);
            __syncthreads();
#pragma unroll
            for (int kk = 16; kk < 32; ++kk) {
                f16x8 A = afrag_lds(sm.planeB, (kk - 16) * 32, ln, q);
                a0 = __builtin_amdgcn_mfma_f32_16x16x32_f16(A, W[kk], a0, 0, 0, 0);
                a1 = __builtin_amdgcn_mfma_f32_16x16x32_f16(A, W[32 + kk], a1, 0, 0, 0);
            }
            if (q < 2) {
#pragma unroll
                for (int r4 = 0; r4 < 4; ++r4) {
                    sm.g[w][q * 4 + r4][ln] = a0[r4];
                    sm.g[w][q * 4 + r4][16 + ln] = a1[r4];
                }
            }
            __syncthreads();
            {
                int b = tid >> 5, u = tid & 31;
                float gi = sm.g[0][b][u] + sm.bias[0][u];
                float gf = sm.g[1][b][u] + sm.bias[1][u];
                float gg = sm.g[2][b][u] + sm.bias[2][u];
                float go = sm.g[3][b][u] + sm.bias[3][u];
                float iv = sigm_(gi), fv = sigm_(gf), gv = tanh_(gg), ov = sigm_(go);
                float c = sm.c[b][u];
                float cn = fv * c + iv * gv;
                sm.c[b][u] = cn;
                sm.hout[b][u] = (f16)(ov * tanh_(cn));
            }
            __syncthreads();
            if (tid < 64) {
                int b = tid >> 3, j = tid & 7;
                u64 v = *(const u64*)&sm.hout[b][j * 4];
                __hip_atomic_store((u64*)(H1g + wr * 4096 + (r << 8) + (b << 5) + (j << 2)),
                                   v, __ATOMIC_RELAXED, __HIP_MEMORY_SCOPE_SYSTEM);
                asm volatile("s_waitcnt vmcnt(0)" ::: "memory");
                if (tid == 0)
                    __hip_atomic_store(flag1 + r, t + 1, __ATOMIC_RELAXED,
                                       __HIP_MEMORY_SCOPE_SYSTEM);
            }

            // ---- out-proj(t-1) AFTER publish, from LDS planeB (off path) --
            if (t > 0) {
                int p = tid >> 4, kp = tid & 15;
                int valid = (p < 10);
                int idx = r * 10 + p;
                int b = valid ? idx / 20 : 0, o = valid ? idx % 20 : 0;
                float a = 0.f;
                if (valid) {
                    const f16* hp = sm.planeB + b * HP_STRIDE + kp * 32;
                    const float* wo = Wo + (size_t)o * 512 + kp * 32;
#pragma unroll
                    for (int k = 0; k < 32; k += 8) {
                        f16x8 hv = *(const f16x8*)(hp + k);
                        float4 wa = *(const float4*)(wo + k);
                        float4 wb = *(const float4*)(wo + k + 4);
                        a += (float)hv[0] * wa.x + (float)hv[1] * wa.y +
                             (float)hv[2] * wa.z + (float)hv[3] * wa.w +
                             (float)hv[4] * wb.x + (float)hv[5] * wb.y +
                             (float)hv[6] * wb.z + (float)hv[7] * wb.w;
                    }
                }
                a += __shfl_down(a, 8, 16);
                a += __shfl_down(a, 4, 16);
                a += __shfl_down(a, 2, 16);
                a += __shfl_down(a, 1, 16);
                if (valid && kp == 0)
                    out[((size_t)(gb8 + b) * 1024 + (t - 1)) * 20 + o] =
                        sigm_(a + bo[o]);
            }
        }

        // ===== epilogue: out(T-1) from h1(T-1) =============================
        wait_flags(flag1, T_STEPS, flag1, T_STEPS, lane);
        stage_plane(H1g + ((T_STEPS - 1) & 1) * 4096, sm.planeB, tid);
        __syncthreads();
        {
            int p = tid >> 4, kp = tid & 15;
            int valid = (p < 10);
            int idx = r * 10 + p;
            int b = valid ? idx / 20 : 0, o = valid ? idx % 20 : 0;
            float a = 0.f;
            if (valid) {
                const f16* hp = sm.planeB + b * HP_STRIDE + kp * 32;
                const float* wo = Wo + (size_t)o * 512 + kp * 32;
#pragma unroll
                for (int k = 0; k < 32; k += 8) {
                    f16x8 hv = *(const f16x8*)(hp + k);
                    float4 wa = *(const float4*)(wo + k);
                    float4 wb = *(const float4*)(wo + k + 4);
                    a += (float)hv[0] * wa.x + (float)hv[1] * wa.y +
                         (float)hv[2] * wa.z + (float)hv[3] * wa.w +
                         (float)hv[4] * wb.x + (float)hv[5] * wb.y +
                         (float)hv[6] * wb.z + (float)hv[7] * wb.w;
                }
            }
            a += __shfl_down(a, 8, 16);
            a += __shfl_down(a, 4, 16);
            a += __shfl_down(a, 2, 16);
            a += __shfl_down(a, 1, 16);
            if (valid && kp == 0)
                out[((size_t)(gb8 + b) * 1024 + (T_STEPS - 1)) * 20 + o] =
                    sigm_(a + bo[o]);
        }
    }
}

extern "C" void kernel_launch(void* const* d_in, const int* in_sizes, int n_in,
                              void* d_out, int out_size, void* d_ws, size_t ws_size,
                              hipStream_t stream) {
    const float* x   = (const float*)d_in[0];
    const float* Wx0 = (const float*)d_in[1];
    const float* bx0 = (const float*)d_in[2];
    const float* Wh0 = (const float*)d_in[3];
    const float* Wx1 = (const float*)d_in[4];
    const float* bx1 = (const float*)d_in[5];
    const float* Wh1 = (const float*)d_in[6];
    const float* Wo  = (const float*)d_in[7];
    const float* bo  = (const float*)d_in[8];
    float* out = (float*)d_out;
    char*  ws  = (char*)d_ws;

    if (ws_size < (size_t)WS_NEED) return;   // fail visibly (out stays poisoned)

    zero_ws_kernel<<<128, 256, 0, stream>>>((unsigned*)ws, WS_NEED / 4);
    lstm_persist<<<256, 256, 0, stream>>>(x, Wx0, bx0, Wh0, Wx1, bx1, Wh1,
                                          Wo, bo, out, ws);
}